// Round 1
// 1382.328 us; speedup vs baseline: 1.5428x; 1.5428x over previous
//
#include <hip/hip_runtime.h>
#include <math.h>

#define HIDN 1024
#define NHEADS 16
#define HD 64
#define NB 2
#define SL 2048

typedef __bf16 bf16x8 __attribute__((ext_vector_type(8)));
typedef float f32x4 __attribute__((ext_vector_type(4)));

__device__ __forceinline__ unsigned short f2bf(float f) {
    unsigned int u = __float_as_uint(f);
    return (unsigned short)((u + 0x7fffu + ((u >> 16) & 1u)) >> 16);
}

// ---------------------------------------------------------------------------
// Generic tiled fp32 GEMM with bias: C[M][N] = A[M][K] @ W[K][N] + bias[N]
// 64x64 tile, BK=32, 256 threads, 4x4 per thread. (fp32 output - used for Wo)
// ---------------------------------------------------------------------------
__global__ __launch_bounds__(256) void gemm_bias_kernel(
    const float* __restrict__ A, const float* __restrict__ W,
    const float* __restrict__ bias, float* __restrict__ C,
    int M, int N, int K)
{
    __shared__ float As[64][33];
    __shared__ float Ws[32][65];
    const int t = threadIdx.x;
    const int tx = t & 15, ty = t >> 4;
    const int m0 = blockIdx.y * 64, n0 = blockIdx.x * 64;
    float acc[4][4] = {};

    for (int k0 = 0; k0 < K; k0 += 32) {
        #pragma unroll
        for (int i = 0; i < 8; i++) {
            int idx = t + i * 256;
            int m = idx >> 5, kk = idx & 31;
            As[m][kk] = A[(size_t)(m0 + m) * K + k0 + kk];
        }
        #pragma unroll
        for (int i = 0; i < 8; i++) {
            int idx = t + i * 256;
            int kk = idx >> 6, n = idx & 63;
            Ws[kk][n] = W[(size_t)(k0 + kk) * N + n0 + n];
        }
        __syncthreads();
        #pragma unroll
        for (int kk = 0; kk < 32; kk++) {
            float a[4], b[4];
            #pragma unroll
            for (int i = 0; i < 4; i++) a[i] = As[ty * 4 + i][kk];
            #pragma unroll
            for (int j = 0; j < 4; j++) b[j] = Ws[kk][tx * 4 + j];
            #pragma unroll
            for (int i = 0; i < 4; i++)
                #pragma unroll
                for (int j = 0; j < 4; j++) acc[i][j] += a[i] * b[j];
        }
        __syncthreads();
    }
    #pragma unroll
    for (int i = 0; i < 4; i++) {
        int m = m0 + ty * 4 + i;
        #pragma unroll
        for (int j = 0; j < 4; j++) {
            int n = n0 + tx * 4 + j;
            C[(size_t)m * N + n] = acc[i][j] + bias[n];
        }
    }
}

// ---------------------------------------------------------------------------
// Same GEMM but bf16 output (row-major). Used for Q and K projections.
// ---------------------------------------------------------------------------
__global__ __launch_bounds__(256) void gemm_bias_bf16_kernel(
    const float* __restrict__ A, const float* __restrict__ W,
    const float* __restrict__ bias, unsigned short* __restrict__ C,
    int M, int N, int K)
{
    __shared__ float As[64][33];
    __shared__ float Ws[32][65];
    const int t = threadIdx.x;
    const int tx = t & 15, ty = t >> 4;
    const int m0 = blockIdx.y * 64, n0 = blockIdx.x * 64;
    float acc[4][4] = {};

    for (int k0 = 0; k0 < K; k0 += 32) {
        #pragma unroll
        for (int i = 0; i < 8; i++) {
            int idx = t + i * 256;
            int m = idx >> 5, kk = idx & 31;
            As[m][kk] = A[(size_t)(m0 + m) * K + k0 + kk];
        }
        #pragma unroll
        for (int i = 0; i < 8; i++) {
            int idx = t + i * 256;
            int kk = idx >> 6, n = idx & 63;
            Ws[kk][n] = W[(size_t)(k0 + kk) * N + n0 + n];
        }
        __syncthreads();
        #pragma unroll
        for (int kk = 0; kk < 32; kk++) {
            float a[4], b[4];
            #pragma unroll
            for (int i = 0; i < 4; i++) a[i] = As[ty * 4 + i][kk];
            #pragma unroll
            for (int j = 0; j < 4; j++) b[j] = Ws[kk][tx * 4 + j];
            #pragma unroll
            for (int i = 0; i < 4; i++)
                #pragma unroll
                for (int j = 0; j < 4; j++) acc[i][j] += a[i] * b[j];
        }
        __syncthreads();
    }
    #pragma unroll
    for (int i = 0; i < 4; i++) {
        int m = m0 + ty * 4 + i;
        #pragma unroll
        for (int j = 0; j < 4; j++) {
            int n = n0 + tx * 4 + j;
            C[(size_t)m * N + n] = f2bf(acc[i][j] + bias[n]);
        }
    }
}

// ---------------------------------------------------------------------------
// GEMM with bf16 TRANSPOSED output: Ct[b][n][l] where m = b*SL + l.
// Used for V projection -> V^T layout for coalesced MFMA B-fragments.
// ---------------------------------------------------------------------------
__global__ __launch_bounds__(256) void gemm_bias_bf16_vt_kernel(
    const float* __restrict__ A, const float* __restrict__ W,
    const float* __restrict__ bias, unsigned short* __restrict__ Ct,
    int M, int N, int K)
{
    __shared__ float As[64][33];
    __shared__ float Ws[32][65];
    const int t = threadIdx.x;
    const int tx = t & 15, ty = t >> 4;
    const int m0 = blockIdx.y * 64, n0 = blockIdx.x * 64;
    float acc[4][4] = {};

    for (int k0 = 0; k0 < K; k0 += 32) {
        #pragma unroll
        for (int i = 0; i < 8; i++) {
            int idx = t + i * 256;
            int m = idx >> 5, kk = idx & 31;
            As[m][kk] = A[(size_t)(m0 + m) * K + k0 + kk];
        }
        #pragma unroll
        for (int i = 0; i < 8; i++) {
            int idx = t + i * 256;
            int kk = idx >> 6, n = idx & 63;
            Ws[kk][n] = W[(size_t)(k0 + kk) * N + n0 + n];
        }
        __syncthreads();
        #pragma unroll
        for (int kk = 0; kk < 32; kk++) {
            float a[4], b[4];
            #pragma unroll
            for (int i = 0; i < 4; i++) a[i] = As[ty * 4 + i][kk];
            #pragma unroll
            for (int j = 0; j < 4; j++) b[j] = Ws[kk][tx * 4 + j];
            #pragma unroll
            for (int i = 0; i < 4; i++)
                #pragma unroll
                for (int j = 0; j < 4; j++) acc[i][j] += a[i] * b[j];
        }
        __syncthreads();
    }
    #pragma unroll
    for (int i = 0; i < 4; i++) {
        int m = m0 + ty * 4 + i;
        int bb = m / SL, l = m % SL;
        #pragma unroll
        for (int j = 0; j < 4; j++) {
            int n = n0 + tx * 4 + j;
            Ct[((size_t)bb * N + n) * SL + l] = f2bf(acc[i][j] + bias[n]);
        }
    }
}

// ---------------------------------------------------------------------------
// Fused attention: energy (QK^T/8) + softmax + att write + PV, bf16 MFMA.
//
// Grid: (SL/64, NB*NHEADS), 256 threads = 4 independent waves.
// Each wave owns 16 q rows.
//  Pass 1: swapped mfma(K,Q) -> lane-local softmax denominator (no cross-lane
//          work per tile; 2 shfl_xor at the end).
//  Pass 2: mfma(Q,K) -> P = exp(S)/l; write att (coalesced); P -> LDS ->
//          re-fragment as A-operand; X += P @ V via mfma with V^T B-frags.
// A/B frags on both sides of every mfma use the identical lane->k mapping,
// so results are invariant to the HW k-permutation. C/D layout
// (col = lane&15, row = (lane>>4)*4 + reg) is the HW-verified mapping.
// ---------------------------------------------------------------------------
__global__ __launch_bounds__(256) void attn_fused_kernel(
    const unsigned short* __restrict__ Qb,   // [NB*SL][HIDN] bf16
    const unsigned short* __restrict__ Kb,   // [NB*SL][HD]   bf16
    const unsigned short* __restrict__ Vt,   // [NB][HD][SL]  bf16 (V^T)
    float* __restrict__ att,                 // [NB*NHEADS][SL][SL]
    float* __restrict__ X)                   // [NB*SL][HIDN]
{
    __shared__ unsigned short Plds[4][16][40];   // per-wave P tile (padded)

    const int t = threadIdx.x;
    const int w = t >> 6;
    const int lane = t & 63;
    const int lr = lane & 15;     // row/col-in-16 index
    const int lg = lane >> 4;     // k-group 0..3

    const int bh = blockIdx.y;    // b*16 + h
    const int b = bh >> 4, h = bh & 15;
    const int q0 = blockIdx.x * 64 + w * 16;

    // Q fragments for this wave's 16 rows (2 halves of d=64). Kept in regs.
    const unsigned short* qrow =
        Qb + ((size_t)(b * SL + q0 + lr)) * HIDN + h * HD + lg * 8;
    const bf16x8 qf0 = *(const bf16x8*)(qrow);
    const bf16x8 qf1 = *(const bf16x8*)(qrow + 32);

    const unsigned short* kbase = Kb + (size_t)b * SL * HD + lg * 8;

    // ---- Pass 1: denominators. S^T = K @ Q^T -> lane owns q = lr. ----
    float ls0 = 0.f, ls1 = 0.f, ls2 = 0.f, ls3 = 0.f;
    for (int k0 = 0; k0 < SL; k0 += 16) {
        const unsigned short* krow = kbase + (size_t)(k0 + lr) * HD;
        bf16x8 kf0 = *(const bf16x8*)(krow);
        bf16x8 kf1 = *(const bf16x8*)(krow + 32);
        f32x4 acc = {0.f, 0.f, 0.f, 0.f};
        acc = __builtin_amdgcn_mfma_f32_16x16x32_bf16(kf0, qf0, acc, 0, 0, 0);
        acc = __builtin_amdgcn_mfma_f32_16x16x32_bf16(kf1, qf1, acc, 0, 0, 0);
        ls0 += __expf(acc[0] * 0.125f);
        ls1 += __expf(acc[1] * 0.125f);
        ls2 += __expf(acc[2] * 0.125f);
        ls3 += __expf(acc[3] * 0.125f);
    }
    float lsum = (ls0 + ls1) + (ls2 + ls3);
    lsum += __shfl_xor(lsum, 16);
    lsum += __shfl_xor(lsum, 32);
    const float inv = 1.f / lsum;      // valid for q = q0 + lr (all lanes)

    // inv for the C-layout rows this lane will hold in pass 2
    float invr[4];
    #pragma unroll
    for (int r = 0; r < 4; r++) invr[r] = __shfl(inv, lg * 4 + r);

    // ---- Pass 2: att write + X = P @ V ----
    const unsigned short* vbase = Vt + (size_t)b * HD * SL;
    float* attb = att + ((size_t)bh * SL + q0) * SL;
    unsigned short* pl = &Plds[w][0][0];

    f32x4 xacc[4];
    #pragma unroll
    for (int n = 0; n < 4; n++) xacc[n] = (f32x4){0.f, 0.f, 0.f, 0.f};

    for (int k0 = 0; k0 < SL; k0 += 32) {
        #pragma unroll
        for (int half = 0; half < 2; half++) {
            const int kk = k0 + half * 16;
            const unsigned short* krow = kbase + (size_t)(kk + lr) * HD;
            bf16x8 kf0 = *(const bf16x8*)(krow);
            bf16x8 kf1 = *(const bf16x8*)(krow + 32);
            f32x4 acc = {0.f, 0.f, 0.f, 0.f};
            acc = __builtin_amdgcn_mfma_f32_16x16x32_bf16(qf0, kf0, acc, 0, 0, 0);
            acc = __builtin_amdgcn_mfma_f32_16x16x32_bf16(qf1, kf1, acc, 0, 0, 0);
            #pragma unroll
            for (int r = 0; r < 4; r++) {
                float p = __expf(acc[r] * 0.125f) * invr[r];
                attb[(size_t)(lg * 4 + r) * SL + kk + lr] = p;
                pl[(lg * 4 + r) * 40 + half * 16 + lr] = f2bf(p);
            }
        }
        // wave-local LDS roundtrip to re-fragment P as an A-operand
        asm volatile("s_waitcnt lgkmcnt(0)" ::: "memory");
        bf16x8 pf = *(const bf16x8*)(pl + lr * 40 + lg * 8);
        #pragma unroll
        for (int n = 0; n < 4; n++) {
            const unsigned short* vrow =
                vbase + (size_t)(n * 16 + lr) * SL + k0 + lg * 8;
            bf16x8 vf = *(const bf16x8*)(vrow);
            xacc[n] = __builtin_amdgcn_mfma_f32_16x16x32_bf16(pf, vf, xacc[n], 0, 0, 0);
        }
    }

    // X write: row = q0 + lg*4 + r, col = h*64 + n*16 + lr
    float* xb = X + ((size_t)(b * SL + q0)) * HIDN + h * HD;
    #pragma unroll
    for (int n = 0; n < 4; n++)
        #pragma unroll
        for (int r = 0; r < 4; r++)
            xb[(size_t)(lg * 4 + r) * HIDN + n * 16 + lr] = xacc[n][r];
}

// ---------------------------------------------------------------------------
extern "C" void kernel_launch(void* const* d_in, const int* in_sizes, int n_in,
                              void* d_out, int out_size, void* d_ws, size_t ws_size,
                              hipStream_t stream)
{
    const float* query = (const float*)d_in[0];
    const float* key   = (const float*)d_in[1];
    const float* value = (const float*)d_in[2];
    const float* Wq = (const float*)d_in[3];
    const float* bq = (const float*)d_in[4];
    const float* Wk = (const float*)d_in[5];
    const float* bk = (const float*)d_in[6];
    const float* Wv = (const float*)d_in[7];
    const float* bv = (const float*)d_in[8];
    const float* Wo = (const float*)d_in[9];
    const float* bo = (const float*)d_in[10];

    float* out = (float*)d_out;                               // [B, L, HID]
    float* att = (float*)d_out + (size_t)NB * SL * HIDN;      // [B, H, L, L]

    const int M = NB * SL;   // 4096

    unsigned short* Qb  = (unsigned short*)d_ws;              // [4096][1024] bf16
    unsigned short* Kb  = Qb + (size_t)M * HIDN;              // [4096][64]   bf16
    unsigned short* Vtb = Kb + (size_t)M * HD;                // [2][64][2048] bf16
    float* Xw = (float*)(Vtb + (size_t)M * HD);               // [4096][1024] fp32

    // Projections (bf16 outputs feed the MFMA attention kernel)
    gemm_bias_bf16_kernel<<<dim3(HIDN / 64, M / 64), 256, 0, stream>>>(
        query, Wq, bq, Qb, M, HIDN, HIDN);
    gemm_bias_bf16_kernel<<<dim3(HD / 64, M / 64), 256, 0, stream>>>(
        key, Wk, bk, Kb, M, HD, HIDN);
    gemm_bias_bf16_vt_kernel<<<dim3(HD / 64, M / 64), 256, 0, stream>>>(
        value, Wv, bv, Vtb, M, HD, HIDN);

    // Fused energy + softmax + att write + PV
    attn_fused_kernel<<<dim3(SL / 64, NB * NHEADS), 256, 0, stream>>>(
        Qb, Kb, Vtb, att, Xw);

    // Output projection (fp32)
    gemm_bias_kernel<<<dim3(HIDN / 64, M / 64), 256, 0, stream>>>(
        Xw, Wo, bo, out, M, HIDN, HIDN);
}